// Round 1
// baseline (185.416 us; speedup 1.0000x reference)
//
#include <hip/hip_runtime.h>

#define NN  1024
#define EMB 128
#define HID 128

typedef __attribute__((ext_vector_type(4))) float float4v;
typedef __attribute__((ext_vector_type(8))) short short8;

// gelu_tanh(x) = x * sigmoid(2*sqrt(2/pi)*(x + 0.044715 x^3))
// exp folded to exp2: constants pre-multiplied by log2(e).
// Max abs deviation from exact erf-GELU ~4e-4 (at |x|~3) — well inside the
// 5.2e-3 output threshold after propagation through random-sign W2/W3.
__device__ __forceinline__ float gelu_fast(float x) {
  float x2 = x * x;
  float t = __builtin_fmaf(0.1029432f, x2, 2.3022086f);  // 2*sqrt(2/pi)*log2e * (1 + 0.044715 x^2)
  float e = __builtin_amdgcn_exp2f(x * t);               // e^{2*inner}
  float r = __builtin_amdgcn_rcpf(1.0f + e);
  return __builtin_fmaf(-x, r, x);                       // x*(1 - 1/(1+e)) = x*sigmoid(2*inner)
}

// ---------------------------------------------------------------------------
// prep: A'[j,h] = z1[j,:]·W1a[h,:] + b1[h]   (blocks 0..1023)
//       B [i,h] = z2[i,:]·W1b[h,:]           (blocks 1024..2047)
//       W2f     = bf16(W2) pre-swizzled into MFMA B-fragment read order
//                 element (kt,nt,lane,j) = W2[nt*16+(lane&15)][kt*32+(lane>>4)*8+j]
//                 (blocks 2048..2063)
// ---------------------------------------------------------------------------
__global__ void prep_kernel(const float* __restrict__ z1, const float* __restrict__ z2,
                            const float* __restrict__ W1, const float* __restrict__ b1,
                            const float* __restrict__ W2,
                            float* __restrict__ Abuf, float* __restrict__ Bbuf,
                            unsigned short* __restrict__ W2f) {
  int blk = blockIdx.x;
  int tid = threadIdx.x;  // 128 threads
  if (blk < 2 * NN) {
    int which = blk >> 10;          // 0 -> A (z1,W1a,+b1), 1 -> B (z2,W1b)
    int row = blk & (NN - 1);
    const float* z = which ? z2 : z1;
    __shared__ __align__(16) float zs[EMB];
    zs[tid] = z[row * EMB + tid];
    __syncthreads();
    const float4v* wrow = (const float4v*)(W1 + tid * (2 * EMB) + which * EMB);
    const float4v* zv = (const float4v*)zs;
    float acc = which ? 0.0f : b1[tid];
#pragma unroll
    for (int d = 0; d < EMB / 4; ++d) {
      float4v wv = wrow[d];
      float4v zz = zv[d];
      acc += zz[0] * wv[0] + zz[1] * wv[1] + zz[2] * wv[2] + zz[3] * wv[3];
    }
    (which ? Bbuf : Abuf)[row * HID + tid] = acc;
  } else {
    int idx = (blk - 2 * NN) * 1024 + tid * 8;   // 16 blocks * 1024 = 16384 elems
    int lane = (idx >> 3) & 63;
    int nt = (idx >> 9) & 7;
    int kt = idx >> 12;
    int g = nt * 16 + (lane & 15);
    int hb = kt * 32 + (lane >> 4) * 8;
#pragma unroll
    for (int j = 0; j < 8; ++j) {
      unsigned u = __float_as_uint(W2[g * HID + hb + j]);
      W2f[idx + j] = (unsigned short)((u + 0x7FFFu + ((u >> 16) & 1u)) >> 16);  // RNE
    }
  }
}

// ---------------------------------------------------------------------------
// main: one block = 16x16 (i,j) tile. 256-row x 128-col x 128-K bf16 MFMA GEMM,
// h1 generated on the fly in A-fragment layout, gelu epilogue + W3 dot fused.
//   m = i_loc*16 + j_loc;  wave w handles m in [w*64, w*64+64)
//   A-frag (16x16x32): lane holds A[m=lane&15][k=quad*8+j]  -> j_loc = lane&15,
//   i_loc = w*4+mt (constant per m-tile)
//   C-layout: col(g) = lane&15, row = quad*4 + reg
// ---------------------------------------------------------------------------
__global__ __launch_bounds__(256, 2)
void fused_mlp_kernel(const float* __restrict__ Abuf, const float* __restrict__ Bbuf,
                      const float* __restrict__ W2f4,  // packed bf16 frags, read as float4
                      const float* __restrict__ b2, const float* __restrict__ W3,
                      const float* __restrict__ b3, float* __restrict__ out) {
  __shared__ __align__(16) short s_w2[HID * HID];  // 32 KB, fragment order

  int tid = threadIdx.x;
  {
    const float4v* src = (const float4v*)W2f4;
    float4v* dst = (float4v*)s_w2;
#pragma unroll
    for (int t = 0; t < 8; ++t)
      dst[tid + t * 256] = src[tid + t * 256];
  }

  int w = tid >> 6;
  int l = tid & 63;
  int r = l & 15;
  int q = l >> 4;

  int bi = (blockIdx.x >> 6) << 4;
  int bj = (blockIdx.x & 63) << 4;

  const float* Arow = Abuf + (bj + r) * HID;            // A'[j = bj+r][h]
  const float* Bbase = Bbuf + (bi + (w << 2)) * HID;    // B[i = bi+w*4+mt][h]

  float4v acc[4][8] = {};

  __syncthreads();

#pragma unroll
  for (int kt = 0; kt < 4; ++kt) {
    int h0 = kt * 32 + q * 8;
    float4v a0 = *(const float4v*)(Arow + h0);
    float4v a1 = *(const float4v*)(Arow + h0 + 4);
    short8 bfr[8];
#pragma unroll
    for (int nt = 0; nt < 8; ++nt)
      bfr[nt] = ((const short8*)s_w2)[(kt * 8 + nt) * 64 + l];  // stride-16B, conflict-free
#pragma unroll
    for (int mt = 0; mt < 4; ++mt) {
      const float* Brow = Bbase + mt * HID + h0;
      float4v c0 = *(const float4v*)(Brow);
      float4v c1 = *(const float4v*)(Brow + 4);
      short8 af;
#pragma unroll
      for (int j = 0; j < 4; ++j) {
        float g0 = gelu_fast(a0[j] + c0[j]);
        float g1 = gelu_fast(a1[j] + c1[j]);
        af[j]     = (short)((__float_as_uint(g0) + 0x8000u) >> 16);  // round-half-up to bf16
        af[j + 4] = (short)((__float_as_uint(g1) + 0x8000u) >> 16);
      }
#pragma unroll
      for (int nt = 0; nt < 8; ++nt)
        acc[mt][nt] = __builtin_amdgcn_mfma_f32_16x16x32_bf16(af, bfr[nt], acc[mt][nt], 0, 0, 0);
    }
  }

  // epilogue: h2 = gelu(acc + b2[g]); out = sum_g h2*W3[g] + b3
  float b2v[8], w3v[8];
#pragma unroll
  for (int nt = 0; nt < 8; ++nt) {
    b2v[nt] = b2[nt * 16 + r];
    w3v[nt] = W3[nt * 16 + r];
  }
  float bias3 = b3[0];

#pragma unroll
  for (int mt = 0; mt < 4; ++mt) {
    float4v s = {0.f, 0.f, 0.f, 0.f};
#pragma unroll
    for (int nt = 0; nt < 8; ++nt) {
      float4v x = acc[mt][nt];
#pragma unroll
      for (int reg = 0; reg < 4; ++reg)
        s[reg] = __builtin_fmaf(gelu_fast(x[reg] + b2v[nt]), w3v[nt], s[reg]);
    }
    // reduce over the 16 g-lanes (xor 1,2,4,8 stays within quad's lane group)
#pragma unroll
    for (int mask = 1; mask < 16; mask <<= 1) {
#pragma unroll
      for (int reg = 0; reg < 4; ++reg)
        s[reg] += __shfl_xor(s[reg], mask, 64);
    }
    if (r < 4) {
      int irow = bi + (w << 2) + mt;          // i
      int jcol = bj + q * 4 + r;              // j = j_loc = quad*4 + reg(=r)
      out[irow * NN + jcol] = s[r] + bias3;
    }
  }
}

extern "C" void kernel_launch(void* const* d_in, const int* in_sizes, int n_in,
                              void* d_out, int out_size, void* d_ws, size_t ws_size,
                              hipStream_t stream) {
  const float* z1 = (const float*)d_in[0];
  const float* z2 = (const float*)d_in[1];
  const float* W1 = (const float*)d_in[2];
  const float* b1 = (const float*)d_in[3];
  const float* W2 = (const float*)d_in[4];
  const float* b2 = (const float*)d_in[5];
  const float* W3 = (const float*)d_in[6];
  const float* b3 = (const float*)d_in[7];
  float* out = (float*)d_out;

  float* Abuf = (float*)d_ws;                          // 1024*128 f32 = 512 KB
  float* Bbuf = Abuf + NN * HID;                       // 512 KB
  unsigned short* W2f = (unsigned short*)(Bbuf + NN * HID);  // 32 KB bf16 frags

  prep_kernel<<<2 * NN + 16, 128, 0, stream>>>(z1, z2, W1, b1, W2, Abuf, Bbuf, W2f);
  fused_mlp_kernel<<<(NN / 16) * (NN / 16), 256, 0, stream>>>(
      Abuf, Bbuf, (const float*)W2f, b2, W3, b3, out);
}

// Round 2
// 159.497 us; speedup vs baseline: 1.1625x; 1.1625x over previous
//
#include <hip/hip_runtime.h>

#define NN  1024
#define EMB 128
#define HID 128

typedef __attribute__((ext_vector_type(4))) float float4v;
typedef __attribute__((ext_vector_type(8))) short short8;

// vectorized tanh-form GELU: x*sigmoid(2*sqrt(2/pi)*(x+0.044715x^3))
// all mul/fma/add ops on float4v -> v_pk_*_f32; exp2/rcp per-element (trans pipe)
__device__ __forceinline__ float4v gelu4(float4v x) {
  float4v x2 = x * x;
  float4v t = x2 * 0.1029432f + 2.3022086f;   // 2*sqrt(2/pi)*log2e*(1+0.044715x^2)
  float4v y = x * t;
  float4v e;
  e[0] = __builtin_amdgcn_exp2f(y[0]);
  e[1] = __builtin_amdgcn_exp2f(y[1]);
  e[2] = __builtin_amdgcn_exp2f(y[2]);
  e[3] = __builtin_amdgcn_exp2f(y[3]);
  float4v d = e + 1.0f;
  float4v rv;
  rv[0] = __builtin_amdgcn_rcpf(d[0]);
  rv[1] = __builtin_amdgcn_rcpf(d[1]);
  rv[2] = __builtin_amdgcn_rcpf(d[2]);
  rv[3] = __builtin_amdgcn_rcpf(d[3]);
  return x - x * rv;                           // x*sigmoid
}

__device__ __forceinline__ short bfrh(float g) {   // bf16 round-half-up
  return (short)((__float_as_uint(g) + 0x8000u) >> 16);
}

// ---------------------------------------------------------------------------
// prep (MFMA): blocks 0..63  -> Abuf[j,h] = z1[j,:]·W1a[h,:] + b1[h]
//              blocks 64..127-> Bbuf[i,h] = z2[i,:]·W1b[h,:]
//              blocks 128..135 -> W2f: bf16(W2) pre-swizzled into B-frag order
// Each A/B block: 16 rows x 128 h, K=128, one 16x16x32 MFMA chain per n-tile.
// ---------------------------------------------------------------------------
__global__ __launch_bounds__(256)
void prep_kernel(const float* __restrict__ z1, const float* __restrict__ z2,
                 const float* __restrict__ W1, const float* __restrict__ b1,
                 const float* __restrict__ W2,
                 float* __restrict__ Abuf, float* __restrict__ Bbuf,
                 unsigned short* __restrict__ W2f) {
  int blk = blockIdx.x;
  int tid = threadIdx.x;
  if (blk < 128) {
    int which = blk >> 6;           // 0: A (z1,W1a,+b1)  1: B (z2,W1b)
    int j0 = (blk & 63) << 4;
    const float* z = which ? z2 : z1;
    int w = tid >> 6, l = tid & 63, r = l & 15, q = l >> 4;

    const float* zrow = z + (j0 + r) * EMB;                          // A-frag rows
    const float* w1r0 = W1 + (w * 32 + r) * (2 * EMB) + which * EMB; // nt=0 rows
    const float* w1r1 = w1r0 + 16 * (2 * EMB);                       // nt=1 rows

    float4v acc[2] = {};
#pragma unroll
    for (int kt = 0; kt < 4; ++kt) {
      int k0 = kt * 32 + q * 8;
      float4v za = *(const float4v*)(zrow + k0);
      float4v zb = *(const float4v*)(zrow + k0 + 4);
      float4v wa0 = *(const float4v*)(w1r0 + k0);
      float4v wb0 = *(const float4v*)(w1r0 + k0 + 4);
      float4v wa1 = *(const float4v*)(w1r1 + k0);
      float4v wb1 = *(const float4v*)(w1r1 + k0 + 4);
      short8 az, b0f, b1f;
#pragma unroll
      for (int j = 0; j < 4; ++j) {
        az[j] = bfrh(za[j]);  az[j + 4] = bfrh(zb[j]);
        b0f[j] = bfrh(wa0[j]); b0f[j + 4] = bfrh(wb0[j]);
        b1f[j] = bfrh(wa1[j]); b1f[j + 4] = bfrh(wb1[j]);
      }
      acc[0] = __builtin_amdgcn_mfma_f32_16x16x32_bf16(az, b0f, acc[0], 0, 0, 0);
      acc[1] = __builtin_amdgcn_mfma_f32_16x16x32_bf16(az, b1f, acc[1], 0, 0, 0);
    }
    float ba0 = which ? 0.0f : b1[w * 32 + r];
    float ba1 = which ? 0.0f : b1[w * 32 + 16 + r];
    float* dst = which ? Bbuf : Abuf;
#pragma unroll
    for (int reg = 0; reg < 4; ++reg) {
      int row = j0 + q * 4 + reg;
      dst[row * HID + w * 32 + r]      = acc[0][reg] + ba0;
      dst[row * HID + w * 32 + 16 + r] = acc[1][reg] + ba1;
    }
  } else {
    int idx = (blk - 128) * 2048 + tid * 8;     // 8 blocks * 2048 = 16384 elems
    int lane = (idx >> 3) & 63;
    int nt = (idx >> 9) & 7;
    int kt = idx >> 12;
    int g = nt * 16 + (lane & 15);
    int hb = kt * 32 + (lane >> 4) * 8;
#pragma unroll
    for (int j = 0; j < 8; ++j) {
      unsigned u = __float_as_uint(W2[g * HID + hb + j]);
      W2f[idx + j] = (unsigned short)((u + 0x7FFFu + ((u >> 16) & 1u)) >> 16);  // RNE
    }
  }
}

// ---------------------------------------------------------------------------
// main: one block = 8x16 (i,j) tile; wave owns 2 i-rows (mt=2) -> acc[2][8]
// (64 VGPRs) so 4 waves/SIMD fit. h1 generated in A-frag layout on the fly.
// ---------------------------------------------------------------------------
__global__ __launch_bounds__(256, 4)
void fused_mlp_kernel(const float* __restrict__ Abuf, const float* __restrict__ Bbuf,
                      const float* __restrict__ W2f4,  // packed bf16 frags
                      const float* __restrict__ b2, const float* __restrict__ W3,
                      const float* __restrict__ b3, float* __restrict__ out) {
  __shared__ __align__(16) short s_w2[HID * HID];  // 32 KB, fragment order

  int tid = threadIdx.x;
  {
    const float4v* src = (const float4v*)W2f4;
    float4v* dst = (float4v*)s_w2;
#pragma unroll
    for (int t = 0; t < 8; ++t)
      dst[tid + t * 256] = src[tid + t * 256];
  }

  int w = tid >> 6;
  int l = tid & 63;
  int r = l & 15;
  int q = l >> 4;

  int bi = (blockIdx.x >> 6) << 3;   // 128 groups of 8 i-rows
  int bj = (blockIdx.x & 63) << 4;   // 64 groups of 16 j-cols

  const float* Arow = Abuf + (bj + r) * HID;       // A'[j=bj+r][h]
  const float* B0 = Bbuf + (bi + w * 2) * HID;     // B[i=bi+2w]
  const float* B1 = B0 + HID;                      // B[i=bi+2w+1]

  float4v acc[2][8] = {};

  __syncthreads();

#pragma unroll
  for (int kt = 0; kt < 4; ++kt) {
    int h0 = kt * 32 + q * 8;
    float4v a0 = *(const float4v*)(Arow + h0);
    float4v a1 = *(const float4v*)(Arow + h0 + 4);

    float4v g00 = gelu4(a0 + *(const float4v*)(B0 + h0));
    float4v g01 = gelu4(a1 + *(const float4v*)(B0 + h0 + 4));
    float4v g10 = gelu4(a0 + *(const float4v*)(B1 + h0));
    float4v g11 = gelu4(a1 + *(const float4v*)(B1 + h0 + 4));
    short8 af0, af1;
#pragma unroll
    for (int j = 0; j < 4; ++j) {
      af0[j] = bfrh(g00[j]); af0[j + 4] = bfrh(g01[j]);
      af1[j] = bfrh(g10[j]); af1[j + 4] = bfrh(g11[j]);
    }

    const short8* wrow = (const short8*)s_w2 + kt * 8 * 64 + l;
#pragma unroll
    for (int nt = 0; nt < 8; ++nt) {
      short8 bfr = wrow[nt * 64];    // stride-16B, conflict-free
      acc[0][nt] = __builtin_amdgcn_mfma_f32_16x16x32_bf16(af0, bfr, acc[0][nt], 0, 0, 0);
      acc[1][nt] = __builtin_amdgcn_mfma_f32_16x16x32_bf16(af1, bfr, acc[1][nt], 0, 0, 0);
    }
  }

  // epilogue: h2 = gelu(acc + b2[g]); out = sum_g h2*W3[g] + b3
  float b2v[8], w3v[8];
#pragma unroll
  for (int nt = 0; nt < 8; ++nt) {
    b2v[nt] = b2[nt * 16 + r];
    w3v[nt] = W3[nt * 16 + r];
  }
  float bias3 = b3[0];

#pragma unroll
  for (int mt = 0; mt < 2; ++mt) {
    float4v s = {0.f, 0.f, 0.f, 0.f};
#pragma unroll
    for (int nt = 0; nt < 8; ++nt) {
      float4v xx = acc[mt][nt] + b2v[nt];
      s = s + gelu4(xx) * w3v[nt];
    }
#pragma unroll
    for (int mask = 1; mask < 16; mask <<= 1) {
#pragma unroll
      for (int reg = 0; reg < 4; ++reg)
        s[reg] += __shfl_xor(s[reg], mask, 64);
    }
    if (r < 4) {
      int irow = bi + w * 2 + mt;
      int jcol = bj + q * 4 + r;
      out[irow * NN + jcol] = s[r] + bias3;
    }
  }
}

extern "C" void kernel_launch(void* const* d_in, const int* in_sizes, int n_in,
                              void* d_out, int out_size, void* d_ws, size_t ws_size,
                              hipStream_t stream) {
  const float* z1 = (const float*)d_in[0];
  const float* z2 = (const float*)d_in[1];
  const float* W1 = (const float*)d_in[2];
  const float* b1 = (const float*)d_in[3];
  const float* W2 = (const float*)d_in[4];
  const float* b2 = (const float*)d_in[5];
  const float* W3 = (const float*)d_in[6];
  const float* b3 = (const float*)d_in[7];
  float* out = (float*)d_out;

  float* Abuf = (float*)d_ws;                                // 512 KB
  float* Bbuf = Abuf + NN * HID;                             // 512 KB
  unsigned short* W2f = (unsigned short*)(Bbuf + NN * HID);  // 32 KB

  prep_kernel<<<136, 256, 0, stream>>>(z1, z2, W1, b1, W2, Abuf, Bbuf, W2f);
  fused_mlp_kernel<<<(NN / 8) * (NN / 16), 256, 0, stream>>>(
      Abuf, Bbuf, (const float*)W2f, b2, W3, b3, out);
}